// Round 1
// baseline (238.872 us; speedup 1.0000x reference)
//
#include <hip/hip_runtime.h>
#include <hip/hip_bf16.h>

using u16 = unsigned short;
typedef __attribute__((ext_vector_type(8))) short short8v;
typedef __attribute__((ext_vector_type(4))) float f32x4;

#define MFMA16(a, b, c) __builtin_amdgcn_mfma_f32_16x16x32_bf16((a), (b), (c), 0, 0, 0)

static __device__ __forceinline__ u16 f2bf(float x) {
  __hip_bfloat16 h = __float2bfloat16(x);
  return __builtin_bit_cast(u16, h);
}

__global__ __launch_bounds__(256) void cast_f32_bf16(const float* __restrict__ s,
                                                     u16* __restrict__ d, int n) {
  int i = (blockIdx.x * 256 + threadIdx.x) * 4;
  if (i >= n) return;
  float4 v = *reinterpret_cast<const float4*>(s + i);
  ushort4 o;
  o.x = f2bf(v.x); o.y = f2bf(v.y); o.z = f2bf(v.z); o.w = f2bf(v.w);
  *reinterpret_cast<ushort4*>(d + i) = o;
}

// C[M,N] fp32 = A[M,K] bf16  @  Bt[N,K] bf16 ^T.  BM=128 BN=64 BK=32, 256 thr.
__global__ __launch_bounds__(256) void gemm_bt(const u16* __restrict__ A,
                                               const u16* __restrict__ Bt,
                                               float* __restrict__ C,
                                               int M, int N, int K) {
  // stride 40 elems = 80B: 16B-aligned for b128, 20-bank row stride -> <=2-way (free)
  __shared__ u16 As[128][40];
  __shared__ u16 Bs[64][40];
  int bm = blockIdx.x, bn = blockIdx.y;
  int tid = threadIdx.x;
  int wid = tid >> 6, l = tid & 63, lr = l & 15, lg = l >> 4;
  int wr = wid >> 1, wc = wid & 1;  // 2x2 waves, each 64x32 out

  f32x4 acc[4][2];
#pragma unroll
  for (int m = 0; m < 4; m++)
#pragma unroll
    for (int n = 0; n < 2; n++) acc[m][n] = (f32x4){0.f, 0.f, 0.f, 0.f};

  for (int k0 = 0; k0 < K; k0 += 32) {
    __syncthreads();
    // stage A: 128 rows x 32 cols = 512 x 16B chunks
#pragma unroll
    for (int i = 0; i < 2; i++) {
      int c = tid + i * 256;
      int row = c >> 2, seg = c & 3;
      *reinterpret_cast<short8v*>(&As[row][seg * 8]) =
          *reinterpret_cast<const short8v*>(A + (size_t)(bm * 128 + row) * K + k0 + seg * 8);
    }
    {  // stage B: 64 rows x 32 cols = 256 chunks
      int row = tid >> 2, seg = tid & 3;
      *reinterpret_cast<short8v*>(&Bs[row][seg * 8]) =
          *reinterpret_cast<const short8v*>(Bt + (size_t)(bn * 64 + row) * K + k0 + seg * 8);
    }
    __syncthreads();

    short8v af[4], bfr[2];
#pragma unroll
    for (int m = 0; m < 4; m++)
      af[m] = *reinterpret_cast<const short8v*>(&As[wr * 64 + m * 16 + lr][lg * 8]);
#pragma unroll
    for (int n = 0; n < 2; n++)
      bfr[n] = *reinterpret_cast<const short8v*>(&Bs[wc * 32 + n * 16 + lr][lg * 8]);
#pragma unroll
    for (int m = 0; m < 4; m++)
#pragma unroll
      for (int n = 0; n < 2; n++) acc[m][n] = MFMA16(af[m], bfr[n], acc[m][n]);
  }

#pragma unroll
  for (int m = 0; m < 4; m++)
#pragma unroll
    for (int n = 0; n < 2; n++)
#pragma unroll
      for (int r = 0; r < 4; r++) {
        int row = bm * 128 + wr * 64 + m * 16 + lg * 4 + r;
        int col = bn * 64 + wc * 32 + n * 16 + lr;
        C[(size_t)row * N + col] = acc[m][n][r];
      }
}

// fused rotary + rms_norm: one wave per (b,t,h) row of 64.
// src layout (B,T,H,D) fp32; dst layout (B,H,T,D) bf16.
__global__ __launch_bounds__(256) void rope_rms(const float* __restrict__ src,
                                                u16* __restrict__ dst,
                                                const float* __restrict__ cosp,
                                                const float* __restrict__ sinp) {
  int R = blockIdx.x * 4 + (threadIdx.x >> 6);  // R = (b*T + t)*H + h
  int l = threadIdx.x & 63;
  int h = R & 15;
  int bt = R >> 4;          // b*2048 + t
  int t = bt & 2047, b = bt >> 11;

  float v = src[((size_t)R << 6) + l];
  float p = __shfl_xor(v, 32);
  float c = cosp[(t << 5) + (l & 31)];
  float s = sinp[(t << 5) + (l & 31)];
  float r = v * c + ((l < 32) ? p * s : -p * s);
  float sq = r * r;
  sq += __shfl_xor(sq, 32);
  sq += __shfl_xor(sq, 16);
  sq += __shfl_xor(sq, 8);
  sq += __shfl_xor(sq, 4);
  sq += __shfl_xor(sq, 2);
  sq += __shfl_xor(sq, 1);
  float inv = rsqrtf(sq * (1.0f / 64.0f) + 1.1920928955078125e-07f);
  dst[((((size_t)b * 16 + h) * 2048 + t) << 6) + l] = f2bf(r * inv);
}

// sliding-window flash attention. Q,KV: (B,H,T,D) bf16. O: (B,T,H*D) bf16.
// 1 block = (b,h, 64 q rows); 4 waves x 16 q rows. K=V (single kv tensor).
__global__ __launch_bounds__(256) void attn_swa(const u16* __restrict__ Q,
                                                const u16* __restrict__ KV,
                                                u16* __restrict__ O,
                                                const int* __restrict__ winp) {
  const int T = 2048;
  int bid = blockIdx.x;
  int bh = bid >> 5;           // T/64 = 32 q-tiles per (b,h)
  int q0 = (bid & 31) << 6;
  int b = bh >> 4, h = bh & 15;
  int W = *winp;
  int tid = threadIdx.x;
  int wid = tid >> 6, l = tid & 63, lr = l & 15, lg = l >> 4;

  __shared__ u16 Kl[64][72];       // [key][d]  row stride 144B (16B-aligned)
  __shared__ u16 Vt[64][72];       // [d][key]  transposed copy for PV B-frags
  __shared__ u16 Pl[4][16][72];    // per-wave P tile [q][key]

  const u16* Qb = Q + (((size_t)bh * T + q0 + wid * 16 + lr) << 6);
  short8v aq0 = *reinterpret_cast<const short8v*>(Qb + lg * 8);
  short8v aq1 = *reinterpret_cast<const short8v*>(Qb + 32 + lg * 8);

  float m_run[4], l_run[4];
  f32x4 oacc[4];
#pragma unroll
  for (int r = 0; r < 4; r++) { m_run[r] = -1e30f; l_run[r] = 0.f; }
#pragma unroll
  for (int dt = 0; dt < 4; dt++) oacc[dt] = (f32x4){0.f, 0.f, 0.f, 0.f};

  int lo = q0 - W;
  if (lo < 0) lo = 0;
  lo &= ~63;

  for (int kt = lo; kt < q0 + 64; kt += 64) {
    __syncthreads();
    const u16* KVb = KV + (((size_t)bh * T + kt) << 6);
#pragma unroll
    for (int i = 0; i < 2; i++) {
      int c = tid + i * 256;      // 512 x 16B chunks: key = c>>3, seg = c&7
      int key = c >> 3, seg = c & 7;
      short8v v = *reinterpret_cast<const short8v*>(KVb + (key << 6) + seg * 8);
      *reinterpret_cast<short8v*>(&Kl[key][seg * 8]) = v;
#pragma unroll
      for (int j = 0; j < 8; j++) Vt[seg * 8 + j][key] = (u16)v[j];
    }
    __syncthreads();

    // S = Q K^T  (16q x 64keys per wave)
    f32x4 s[4];
#pragma unroll
    for (int nt = 0; nt < 4; nt++) {
      s[nt] = (f32x4){0.f, 0.f, 0.f, 0.f};
      short8v b0 = *reinterpret_cast<const short8v*>(&Kl[nt * 16 + lr][lg * 8]);
      s[nt] = MFMA16(aq0, b0, s[nt]);
      short8v b1 = *reinterpret_cast<const short8v*>(&Kl[nt * 16 + lr][32 + lg * 8]);
      s[nt] = MFMA16(aq1, b1, s[nt]);
    }

    // mask + scale + online softmax (row r lives in lane group lg, lanes lr=0..15)
#pragma unroll
    for (int r = 0; r < 4; r++) {
      int t = q0 + wid * 16 + lg * 4 + r;
      float sv[4];
      float mt = -3e38f;
#pragma unroll
      for (int nt = 0; nt < 4; nt++) {
        int k = kt + nt * 16 + lr;
        float val = ((k <= t) && (t - k <= W)) ? s[nt][r] * 0.125f : -3e38f;
        sv[nt] = val;
        mt = fmaxf(mt, val);
      }
      mt = fmaxf(mt, __shfl_xor(mt, 1));
      mt = fmaxf(mt, __shfl_xor(mt, 2));
      mt = fmaxf(mt, __shfl_xor(mt, 4));
      mt = fmaxf(mt, __shfl_xor(mt, 8));
      float mn = fmaxf(m_run[r], mt);
      float al = __expf(m_run[r] - mn);
      m_run[r] = mn;
      float rs = 0.f;
#pragma unroll
      for (int nt = 0; nt < 4; nt++) {
        float pv = __expf(sv[nt] - mn);
        rs += pv;
        Pl[wid][lg * 4 + r][nt * 16 + lr] = f2bf(pv);
      }
      rs += __shfl_xor(rs, 1);
      rs += __shfl_xor(rs, 2);
      rs += __shfl_xor(rs, 4);
      rs += __shfl_xor(rs, 8);
      l_run[r] = l_run[r] * al + rs;
#pragma unroll
      for (int dt = 0; dt < 4; dt++) oacc[dt][r] *= al;
    }

    // O += P V   (A-frag from Pl, B-frag contiguous rows of Vt)
    short8v ap0 = *reinterpret_cast<const short8v*>(&Pl[wid][lr][lg * 8]);
    short8v ap1 = *reinterpret_cast<const short8v*>(&Pl[wid][lr][32 + lg * 8]);
#pragma unroll
    for (int dt = 0; dt < 4; dt++) {
      short8v v0 = *reinterpret_cast<const short8v*>(&Vt[dt * 16 + lr][lg * 8]);
      oacc[dt] = MFMA16(ap0, v0, oacc[dt]);
      short8v v1 = *reinterpret_cast<const short8v*>(&Vt[dt * 16 + lr][32 + lg * 8]);
      oacc[dt] = MFMA16(ap1, v1, oacc[dt]);
    }
  }

  // epilogue: O (B,T,C) bf16
#pragma unroll
  for (int r = 0; r < 4; r++) {
    int t = q0 + wid * 16 + lg * 4 + r;
    float inv = 1.f / l_run[r];
#pragma unroll
    for (int dt = 0; dt < 4; dt++) {
      O[(((size_t)b * T + t) << 10) + (h << 6) + dt * 16 + lr] = f2bf(oacc[dt][r] * inv);
    }
  }
}

extern "C" void kernel_launch(void* const* d_in, const int* in_sizes, int n_in,
                              void* d_out, int out_size, void* d_ws, size_t ws_size,
                              hipStream_t stream) {
  (void)in_sizes; (void)n_in; (void)out_size; (void)ws_size;
  const float* x    = (const float*)d_in[0];
  const float* cosp = (const float*)d_in[1];
  const float* sinp = (const float*)d_in[2];
  const float* kvw  = (const float*)d_in[3];
  const float* pw   = (const float*)d_in[4];
  const int*   win  = (const int*)d_in[5];

  char* w = (char*)d_ws;
  u16*   xbf   = (u16*)(w);                        // 8MB  (x bf16; later reused as q)
  u16*   kvwbf = (u16*)(w + (8u << 20));           // 2MB
  u16*   pwbf  = (u16*)(w + (10u << 20));          // 2MB
  float* kvf   = (float*)(w + (12u << 20));        // 16MB (kv fp32; later reused as attn out)
  u16*   aout  = (u16*)(w + (12u << 20));          // 8MB  (aliases kvf, dead by then)
  u16*   kvbf  = (u16*)(w + (28u << 20));          // 8MB
  u16*   qbf   = xbf;                              // aliases xbf (dead after GEMM1)

  cast_f32_bf16<<<4096, 256, 0, stream>>>(x, xbf, 4194304);
  cast_f32_bf16<<<1024, 256, 0, stream>>>(kvw, kvwbf, 1048576);
  cast_f32_bf16<<<1024, 256, 0, stream>>>(pw, pwbf, 1048576);

  // kv = x @ kv_w^T   (4096 x 1024 x 1024)
  gemm_bt<<<dim3(32, 16), 256, 0, stream>>>(xbf, kvwbf, kvf, 4096, 1024, 1024);

  // q = rmsnorm(rotary(x)), kv = rmsnorm(rotary(kv)) -> (B,H,T,D) bf16
  rope_rms<<<16384, 256, 0, stream>>>(x, qbf, cosp, sinp);
  rope_rms<<<16384, 256, 0, stream>>>(kvf, kvbf, cosp, sinp);

  // sliding-window attention -> (B,T,C) bf16
  attn_swa<<<1024, 256, 0, stream>>>(qbf, kvbf, aout, win);

  // out = attn_out @ proj_w^T -> fp32
  gemm_bt<<<dim3(32, 16), 256, 0, stream>>>(aout, pwbf, (float*)d_out, 4096, 1024, 1024);
}

// Round 3
// 205.054 us; speedup vs baseline: 1.1649x; 1.1649x over previous
//
#include <hip/hip_runtime.h>
#include <hip/hip_bf16.h>

using u16 = unsigned short;
typedef __attribute__((ext_vector_type(8))) short short8v;
typedef __attribute__((ext_vector_type(4))) float f32x4;

#define MFMA16(a, b, c) __builtin_amdgcn_mfma_f32_16x16x32_bf16((a), (b), (c), 0, 0, 0)

static __device__ __forceinline__ u16 f2bf(float x) {
  __hip_bfloat16 h = __float2bfloat16(x);
  return __builtin_bit_cast(u16, h);
}

__global__ __launch_bounds__(256) void cast_f32_bf16(const float* __restrict__ s,
                                                     u16* __restrict__ d, int n) {
  int i = (blockIdx.x * 256 + threadIdx.x) * 4;
  if (i >= n) return;
  float4 v = *reinterpret_cast<const float4*>(s + i);
  ushort4 o;
  o.x = f2bf(v.x); o.y = f2bf(v.y); o.z = f2bf(v.z); o.w = f2bf(v.w);
  *reinterpret_cast<ushort4*>(d + i) = o;
}

// C[M,N] fp32 = A[M,K] bf16 @ Bt[N,K]^T.  BM=BN=128, BK=32, 4 waves (2x2),
// each wave 64x64 out (4x4 f32x4 acc). Padded-40 LDS rows: frag reads and
// staging writes land on uniform (r+s)%8 bank classes -> ~conflict-free.
__global__ __launch_bounds__(256) void gemm_bt(const u16* __restrict__ A,
                                               const u16* __restrict__ Bt,
                                               float* __restrict__ C,
                                               int M, int N, int K) {
  __shared__ u16 As[128][40];
  __shared__ u16 Bs[128][40];
  int bm = blockIdx.x, bn = blockIdx.y;
  int tid = threadIdx.x;
  int l = tid & 63, lr = l & 15, lg = l >> 4;
  int wid = tid >> 6, wr = wid >> 1, wc = wid & 1;

  int row0 = tid >> 2, seg = tid & 3;   // staging chunk 0; chunk 1 = row0+64
  int row1 = row0 + 64;
  const u16* Ab = A + (size_t)(bm * 128) * K + seg * 8;
  const u16* Bb = Bt + (size_t)(bn * 128) * K + seg * 8;

  f32x4 acc[4][4];
#pragma unroll
  for (int m = 0; m < 4; m++)
#pragma unroll
    for (int n = 0; n < 4; n++) acc[m][n] = (f32x4){0.f, 0.f, 0.f, 0.f};

  // T14: prefetch k-tile 0 into registers
  short8v ra0 = *reinterpret_cast<const short8v*>(Ab + (size_t)row0 * K);
  short8v ra1 = *reinterpret_cast<const short8v*>(Ab + (size_t)row1 * K);
  short8v rb0 = *reinterpret_cast<const short8v*>(Bb + (size_t)row0 * K);
  short8v rb1 = *reinterpret_cast<const short8v*>(Bb + (size_t)row1 * K);

  for (int k0 = 0; k0 < K; k0 += 32) {
    __syncthreads();
    *reinterpret_cast<short8v*>(&As[row0][seg * 8]) = ra0;
    *reinterpret_cast<short8v*>(&As[row1][seg * 8]) = ra1;
    *reinterpret_cast<short8v*>(&Bs[row0][seg * 8]) = rb0;
    *reinterpret_cast<short8v*>(&Bs[row1][seg * 8]) = rb1;
    __syncthreads();
    if (k0 + 32 < K) {   // prefetch next k-tile; HBM latency hides under MFMAs
      ra0 = *reinterpret_cast<const short8v*>(Ab + (size_t)row0 * K + k0 + 32);
      ra1 = *reinterpret_cast<const short8v*>(Ab + (size_t)row1 * K + k0 + 32);
      rb0 = *reinterpret_cast<const short8v*>(Bb + (size_t)row0 * K + k0 + 32);
      rb1 = *reinterpret_cast<const short8v*>(Bb + (size_t)row1 * K + k0 + 32);
    }

    short8v af[4], bfr[4];
#pragma unroll
    for (int m = 0; m < 4; m++)
      af[m] = *reinterpret_cast<const short8v*>(&As[wr * 64 + m * 16 + lr][lg * 8]);
#pragma unroll
    for (int n = 0; n < 4; n++)
      bfr[n] = *reinterpret_cast<const short8v*>(&Bs[wc * 64 + n * 16 + lr][lg * 8]);
#pragma unroll
    for (int m = 0; m < 4; m++)
#pragma unroll
      for (int n = 0; n < 4; n++) acc[m][n] = MFMA16(af[m], bfr[n], acc[m][n]);
  }

#pragma unroll
  for (int m = 0; m < 4; m++)
#pragma unroll
    for (int n = 0; n < 4; n++)
#pragma unroll
      for (int r = 0; r < 4; r++) {
        int row = bm * 128 + wr * 64 + m * 16 + lg * 4 + r;
        int col = bn * 128 + wc * 64 + n * 16 + lr;
        C[(size_t)row * N + col] = acc[m][n][r];
      }
}

// fused rotary + rms_norm: one wave per (b,t,h) row of 64.
// src layout (B,T,H,D) fp32; dst layout (B,H,T,D) bf16.
__global__ __launch_bounds__(256) void rope_rms(const float* __restrict__ src,
                                                u16* __restrict__ dst,
                                                const float* __restrict__ cosp,
                                                const float* __restrict__ sinp) {
  int R = blockIdx.x * 4 + (threadIdx.x >> 6);  // R = (b*T + t)*H + h
  int l = threadIdx.x & 63;
  int h = R & 15;
  int bt = R >> 4;
  int t = bt & 2047, b = bt >> 11;

  float v = src[((size_t)R << 6) + l];
  float p = __shfl_xor(v, 32);
  float c = cosp[(t << 5) + (l & 31)];
  float s = sinp[(t << 5) + (l & 31)];
  float r = v * c + ((l < 32) ? p * s : -p * s);
  float sq = r * r;
  sq += __shfl_xor(sq, 32);
  sq += __shfl_xor(sq, 16);
  sq += __shfl_xor(sq, 8);
  sq += __shfl_xor(sq, 4);
  sq += __shfl_xor(sq, 2);
  sq += __shfl_xor(sq, 1);
  float inv = rsqrtf(sq * (1.0f / 64.0f) + 1.1920928955078125e-07f);
  dst[((((size_t)b * 16 + h) * 2048 + t) << 6) + l] = f2bf(r * inv);
}

// (BH,T,D) -> (BH,D,T) bf16 transpose in 64x64 tiles.
__global__ __launch_bounds__(256) void transpose_td(const u16* __restrict__ src,
                                                    u16* __restrict__ dst) {
  __shared__ u16 Ld[64][72];
  int t0 = blockIdx.x << 6, bh = blockIdx.y;
  int tid = threadIdx.x;
#pragma unroll
  for (int i = 0; i < 2; i++) {
    int c = tid + i * 256, tr = c >> 3, sg = c & 7;
    *reinterpret_cast<short8v*>(&Ld[tr][sg * 8]) =
        *reinterpret_cast<const short8v*>(src + ((size_t)bh * 2048 + t0 + tr) * 64 + sg * 8);
  }
  __syncthreads();
#pragma unroll
  for (int i = 0; i < 2; i++) {
    int c = tid + i * 256, dr = c >> 3, sg = c & 7;
    short8v v;
#pragma unroll
    for (int j = 0; j < 8; j++) v[j] = (short)Ld[sg * 8 + j][dr];
    *reinterpret_cast<short8v*>(dst + ((size_t)bh * 64 + dr) * 2048 + t0 + sg * 8) = v;
  }
}

// sliding-window flash attention. Q,KV: (B,H,T,D) bf16; KVt: (B,H,D,T) bf16.
// O: (B,T,H*D) bf16. 1 block = (b,h, 64 q rows); 4 waves x 16 q rows. K=V.
__global__ __launch_bounds__(256) void attn_swa(const u16* __restrict__ Q,
                                                const u16* __restrict__ KV,
                                                const u16* __restrict__ KVt,
                                                u16* __restrict__ O,
                                                const int* __restrict__ winp) {
  const int T = 2048;
  int bid = blockIdx.x;
  int bh = bid & 31;                 // spread bh across consecutive blocks
  int qi = 31 - (bid >> 5);          // heavy q-tiles dispatched first
  int q0 = qi << 6;
  int b = bh >> 4, h = bh & 15;
  int W = *winp;
  int tid = threadIdx.x;
  int wid = tid >> 6, l = tid & 63, lr = l & 15, lg = l >> 4;

  __shared__ u16 Kl[64][72];       // [key][d]
  __shared__ u16 Vt[64][72];       // [d][key]  (staged from KVt, b128 rows)
  __shared__ u16 Pl[4][16][72];    // per-wave P tile [q][key]

  const u16* Qb = Q + (((size_t)bh * T + q0 + wid * 16 + lr) << 6);
  short8v aq0 = *reinterpret_cast<const short8v*>(Qb + lg * 8);
  short8v aq1 = *reinterpret_cast<const short8v*>(Qb + 32 + lg * 8);

  float m_run[4], l_run[4];
  f32x4 oacc[4];
#pragma unroll
  for (int r = 0; r < 4; r++) { m_run[r] = -1e30f; l_run[r] = 0.f; }
#pragma unroll
  for (int dt = 0; dt < 4; dt++) oacc[dt] = (f32x4){0.f, 0.f, 0.f, 0.f};

  int lo = q0 - W;
  if (lo < 0) lo = 0;
  lo &= ~63;

  const u16* KVbh  = KV + (((size_t)bh * T) << 6);
  const u16* KVtbh = KVt + ((size_t)bh << 6) * T;
  int r8 = tid >> 3, sg = tid & 7;   // staging: rows r8 and r8+32, col seg sg

  // T14: prefetch first tile into registers (issue early / LDS-write late)
  short8v vK0 = *reinterpret_cast<const short8v*>(KVbh + ((size_t)(lo + r8) << 6) + sg * 8);
  short8v vK1 = *reinterpret_cast<const short8v*>(KVbh + ((size_t)(lo + r8 + 32) << 6) + sg * 8);
  short8v vV0 = *reinterpret_cast<const short8v*>(KVtbh + (size_t)r8 * T + lo + sg * 8);
  short8v vV1 = *reinterpret_cast<const short8v*>(KVtbh + (size_t)(r8 + 32) * T + lo + sg * 8);

  for (int kt = lo; kt <= q0; kt += 64) {
    __syncthreads();                 // prev compute done reading LDS
    *reinterpret_cast<short8v*>(&Kl[r8][sg * 8]) = vK0;
    *reinterpret_cast<short8v*>(&Kl[r8 + 32][sg * 8]) = vK1;
    *reinterpret_cast<short8v*>(&Vt[r8][sg * 8]) = vV0;
    *reinterpret_cast<short8v*>(&Vt[r8 + 32][sg * 8]) = vV1;
    __syncthreads();                 // tile ready
    if (kt < q0) {                   // prefetch next tile under compute
      vK0 = *reinterpret_cast<const short8v*>(KVbh + ((size_t)(kt + 64 + r8) << 6) + sg * 8);
      vK1 = *reinterpret_cast<const short8v*>(KVbh + ((size_t)(kt + 64 + r8 + 32) << 6) + sg * 8);
      vV0 = *reinterpret_cast<const short8v*>(KVtbh + (size_t)r8 * T + kt + 64 + sg * 8);
      vV1 = *reinterpret_cast<const short8v*>(KVtbh + (size_t)(r8 + 32) * T + kt + 64 + sg * 8);
    }

    // S = Q K^T  (16q x 64keys per wave)
    f32x4 s[4];
#pragma unroll
    for (int nt = 0; nt < 4; nt++) {
      s[nt] = (f32x4){0.f, 0.f, 0.f, 0.f};
      short8v b0 = *reinterpret_cast<const short8v*>(&Kl[nt * 16 + lr][lg * 8]);
      s[nt] = MFMA16(aq0, b0, s[nt]);
      short8v b1 = *reinterpret_cast<const short8v*>(&Kl[nt * 16 + lr][32 + lg * 8]);
      s[nt] = MFMA16(aq1, b1, s[nt]);
    }

    // mask + scale + online softmax (row r in lane group lg, lanes lr=0..15)
#pragma unroll
    for (int r = 0; r < 4; r++) {
      int t = q0 + wid * 16 + lg * 4 + r;
      float sv[4];
      float mt = -3e38f;
#pragma unroll
      for (int nt = 0; nt < 4; nt++) {
        int k = kt + nt * 16 + lr;
        float val = ((k <= t) && (t - k <= W)) ? s[nt][r] * 0.125f : -3e38f;
        sv[nt] = val;
        mt = fmaxf(mt, val);
      }
      mt = fmaxf(mt, __shfl_xor(mt, 1));
      mt = fmaxf(mt, __shfl_xor(mt, 2));
      mt = fmaxf(mt, __shfl_xor(mt, 4));
      mt = fmaxf(mt, __shfl_xor(mt, 8));
      float mn = fmaxf(m_run[r], mt);
      float al = __expf(m_run[r] - mn);
      m_run[r] = mn;
      float rs = 0.f;
#pragma unroll
      for (int nt = 0; nt < 4; nt++) {
        float pv = __expf(sv[nt] - mn);
        rs += pv;
        Pl[wid][lg * 4 + r][nt * 16 + lr] = f2bf(pv);
      }
      rs += __shfl_xor(rs, 1);
      rs += __shfl_xor(rs, 2);
      rs += __shfl_xor(rs, 4);
      rs += __shfl_xor(rs, 8);
      l_run[r] = l_run[r] * al + rs;
#pragma unroll
      for (int dt = 0; dt < 4; dt++) oacc[dt][r] *= al;
    }

    // O += P V  (A-frag from Pl, B-frag contiguous rows of Vt)
    short8v ap0 = *reinterpret_cast<const short8v*>(&Pl[wid][lr][lg * 8]);
    short8v ap1 = *reinterpret_cast<const short8v*>(&Pl[wid][lr][32 + lg * 8]);
#pragma unroll
    for (int dt = 0; dt < 4; dt++) {
      short8v v0 = *reinterpret_cast<const short8v*>(&Vt[dt * 16 + lr][lg * 8]);
      oacc[dt] = MFMA16(ap0, v0, oacc[dt]);
      short8v v1 = *reinterpret_cast<const short8v*>(&Vt[dt * 16 + lr][32 + lg * 8]);
      oacc[dt] = MFMA16(ap1, v1, oacc[dt]);
    }
  }

  // epilogue: O (B,T,C) bf16
#pragma unroll
  for (int r = 0; r < 4; r++) {
    int t = q0 + wid * 16 + lg * 4 + r;
    float inv = 1.f / l_run[r];
#pragma unroll
    for (int dt = 0; dt < 4; dt++) {
      O[(((size_t)b * T + t) << 10) + (h << 6) + dt * 16 + lr] = f2bf(oacc[dt][r] * inv);
    }
  }
}

extern "C" void kernel_launch(void* const* d_in, const int* in_sizes, int n_in,
                              void* d_out, int out_size, void* d_ws, size_t ws_size,
                              hipStream_t stream) {
  (void)in_sizes; (void)n_in; (void)out_size; (void)ws_size;
  const float* x    = (const float*)d_in[0];
  const float* cosp = (const float*)d_in[1];
  const float* sinp = (const float*)d_in[2];
  const float* kvw  = (const float*)d_in[3];
  const float* pw   = (const float*)d_in[4];
  const int*   win  = (const int*)d_in[5];

  char* w = (char*)d_ws;
  u16*   xbf   = (u16*)(w);                        // 0-8MB: x bf16, then q (B,H,T,D)
  u16*   kvwbf = (u16*)(w + (8u << 20));           // 8-10MB
  u16*   pwbf  = (u16*)(w + (10u << 20));          // 10-12MB
  float* kvf   = (float*)(w + (12u << 20));        // 12-28MB kv fp32 (dead after rope2)
  u16*   kvt   = (u16*)(w + (12u << 20));          // 12-20MB (over dead kvf)
  u16*   aout  = (u16*)(w + (20u << 20));          // 20-28MB (over dead kvf)
  u16*   kvbf  = (u16*)(w + (28u << 20));          // 28-36MB
  u16*   qbf   = xbf;

  cast_f32_bf16<<<4096, 256, 0, stream>>>(x, xbf, 4194304);
  cast_f32_bf16<<<1024, 256, 0, stream>>>(kvw, kvwbf, 1048576);
  cast_f32_bf16<<<1024, 256, 0, stream>>>(pw, pwbf, 1048576);

  // kv = x @ kv_w^T   (4096 x 1024 x 1024)
  gemm_bt<<<dim3(32, 8), 256, 0, stream>>>(xbf, kvwbf, kvf, 4096, 1024, 1024);

  // q = rmsnorm(rotary(x)), kv = rmsnorm(rotary(kv)) -> (B,H,T,D) bf16
  rope_rms<<<16384, 256, 0, stream>>>(x, qbf, cosp, sinp);
  rope_rms<<<16384, 256, 0, stream>>>(kvf, kvbf, cosp, sinp);

  // kvt (B,H,D,T) for the PV B-operand
  transpose_td<<<dim3(32, 32), 256, 0, stream>>>(kvbf, kvt);

  // sliding-window attention -> (B,T,C) bf16
  attn_swa<<<1024, 256, 0, stream>>>(qbf, kvbf, kvt, aout, win);

  // out = attn_out @ proj_w^T -> fp32
  gemm_bt<<<dim3(32, 8), 256, 0, stream>>>(aout, pwbf, (float*)d_out, 4096, 1024, 1024);
}

// Round 4
// 203.922 us; speedup vs baseline: 1.1714x; 1.0056x over previous
//
#include <hip/hip_runtime.h>
#include <hip/hip_bf16.h>

using u16 = unsigned short;
typedef __attribute__((ext_vector_type(8))) short short8v;
typedef __attribute__((ext_vector_type(4))) float f32x4;

#define MFMA16(a, b, c) __builtin_amdgcn_mfma_f32_16x16x32_bf16((a), (b), (c), 0, 0, 0)

#define GLOAD16(g, l) __builtin_amdgcn_global_load_lds(                       \
    (const __attribute__((address_space(1))) void*)(const void*)(g),          \
    (__attribute__((address_space(3))) void*)(void*)(l), 16, 0, 0)

static __device__ __forceinline__ u16 f2bf(float x) {
  __hip_bfloat16 h = __float2bfloat16(x);
  return __builtin_bit_cast(u16, h);
}

__global__ __launch_bounds__(256) void cast_f32_bf16(const float* __restrict__ s,
                                                     u16* __restrict__ d, int n) {
  int i = (blockIdx.x * 256 + threadIdx.x) * 4;
  if (i >= n) return;
  float4 v = *reinterpret_cast<const float4*>(s + i);
  ushort4 o;
  o.x = f2bf(v.x); o.y = f2bf(v.y); o.z = f2bf(v.z); o.w = f2bf(v.w);
  *reinterpret_cast<ushort4*>(d + i) = o;
}

// C[M,N] fp32 = A[M,K] bf16 @ Bt[N,K]^T.  m97-exact staging: linear LDS,
// global_load_lds width=16.  BM=64 BN=128 BK=32, 4 waves (2x2), each 32x64.
// Grid (M/64, N/128) = 512 blocks -> 2 blocks/CU for barrier-drain overlap.
__global__ __launch_bounds__(256) void gemm_bt(const u16* __restrict__ A,
                                               const u16* __restrict__ Bt,
                                               float* __restrict__ C,
                                               int M, int N, int K) {
  __shared__ u16 As[64 * 32];
  __shared__ u16 Bs[128 * 32];
  int bm = blockIdx.x, bn = blockIdx.y;
  int tid = threadIdx.x;
  int wid = tid >> 6, l = tid & 63, lr = l & 15, lg = l >> 4;
  int wr = wid >> 1, wc = wid & 1;

  // staging: per gload a wave covers 16 rows x 32 elems (lane l -> row l>>2,
  // 16B chunk l&3), LDS dest = wave base + l*16B (linear, matches [row][32]).
  int srow = l >> 2, scol = (l & 3) * 8;
  const u16* Ag  = A  + (size_t)(bm * 64 + wid * 16 + srow) * K + scol;
  const u16* Bg0 = Bt + (size_t)(bn * 128 + wid * 32 + srow) * K + scol;
  const u16* Bg1 = Bg0 + (size_t)16 * K;
  u16* Asb  = &As[wid * 512];
  u16* Bsb0 = &Bs[wid * 1024];
  u16* Bsb1 = &Bs[wid * 1024 + 512];

  f32x4 acc[2][4];
#pragma unroll
  for (int m = 0; m < 2; m++)
#pragma unroll
    for (int n = 0; n < 4; n++) acc[m][n] = (f32x4){0.f, 0.f, 0.f, 0.f};

  for (int k0 = 0; k0 < K; k0 += 32) {
    __syncthreads();
    GLOAD16(Ag + k0, Asb);
    GLOAD16(Bg0 + k0, Bsb0);
    GLOAD16(Bg1 + k0, Bsb1);
    __syncthreads();  // compiler drains vmcnt(0) before barrier

    short8v af[2], bfr[4];
#pragma unroll
    for (int m = 0; m < 2; m++)
      af[m] = *reinterpret_cast<const short8v*>(&As[(wr * 32 + m * 16 + lr) * 32 + lg * 8]);
#pragma unroll
    for (int n = 0; n < 4; n++)
      bfr[n] = *reinterpret_cast<const short8v*>(&Bs[(wc * 64 + n * 16 + lr) * 32 + lg * 8]);
#pragma unroll
    for (int m = 0; m < 2; m++)
#pragma unroll
      for (int n = 0; n < 4; n++) acc[m][n] = MFMA16(af[m], bfr[n], acc[m][n]);
  }

#pragma unroll
  for (int m = 0; m < 2; m++)
#pragma unroll
    for (int n = 0; n < 4; n++)
#pragma unroll
      for (int r = 0; r < 4; r++) {
        int row = bm * 64 + wr * 32 + m * 16 + lg * 4 + r;
        int col = bn * 128 + wc * 64 + n * 16 + lr;
        C[(size_t)row * N + col] = acc[m][n][r];
      }
}

// fused rotary + rms_norm (+ output scale): one wave per (b,t,h) row of 64.
// src layout (B,T,H,D) fp32; dst layout (B,H,T,D) bf16.
__global__ __launch_bounds__(256) void rope_rms(const float* __restrict__ src,
                                                u16* __restrict__ dst,
                                                const float* __restrict__ cosp,
                                                const float* __restrict__ sinp,
                                                float scale) {
  int R = blockIdx.x * 4 + (threadIdx.x >> 6);  // R = (b*T + t)*H + h
  int l = threadIdx.x & 63;
  int h = R & 15;
  int bt = R >> 4;
  int t = bt & 2047, b = bt >> 11;

  float v = src[((size_t)R << 6) + l];
  float p = __shfl_xor(v, 32);
  float c = cosp[(t << 5) + (l & 31)];
  float s = sinp[(t << 5) + (l & 31)];
  float r = v * c + ((l < 32) ? p * s : -p * s);
  float sq = r * r;
  sq += __shfl_xor(sq, 32);
  sq += __shfl_xor(sq, 16);
  sq += __shfl_xor(sq, 8);
  sq += __shfl_xor(sq, 4);
  sq += __shfl_xor(sq, 2);
  sq += __shfl_xor(sq, 1);
  float inv = rsqrtf(sq * (1.0f / 64.0f) + 1.1920928955078125e-07f) * scale;
  dst[((((size_t)b * 16 + h) * 2048 + t) << 6) + l] = f2bf(r * inv);
}

// (BH,T,D) -> (BH,D,T) bf16 transpose in 64x64 tiles.
__global__ __launch_bounds__(256) void transpose_td(const u16* __restrict__ src,
                                                    u16* __restrict__ dst) {
  __shared__ u16 Ld[64][72];
  int t0 = blockIdx.x << 6, bh = blockIdx.y;
  int tid = threadIdx.x;
#pragma unroll
  for (int i = 0; i < 2; i++) {
    int c = tid + i * 256, tr = c >> 3, sg = c & 7;
    *reinterpret_cast<short8v*>(&Ld[tr][sg * 8]) =
        *reinterpret_cast<const short8v*>(src + ((size_t)bh * 2048 + t0 + tr) * 64 + sg * 8);
  }
  __syncthreads();
#pragma unroll
  for (int i = 0; i < 2; i++) {
    int c = tid + i * 256, dr = c >> 3, sg = c & 7;
    short8v v;
#pragma unroll
    for (int j = 0; j < 8; j++) v[j] = (short)Ld[sg * 8 + j][dr];
    *reinterpret_cast<short8v*>(dst + ((size_t)bh * 64 + dr) * 2048 + t0 + sg * 8) = v;
  }
}

// sliding-window flash attention. Q: (B,H,T,D) bf16 PRE-SCALED by 0.125*log2e;
// KV: (B,H,T,D); KVt: (B,H,D,T). O: (B,T,H*D) bf16. Softmax in exp2 domain.
// 1 block = (b,h, 64 q rows); 4 waves x 16 q rows. K=V (single kv tensor).
__global__ __launch_bounds__(256) void attn_swa(const u16* __restrict__ Q,
                                                const u16* __restrict__ KV,
                                                const u16* __restrict__ KVt,
                                                u16* __restrict__ O,
                                                const int* __restrict__ winp) {
  const int T = 2048;
  int bid = blockIdx.x;
  int bh = bid & 31;                 // spread bh across consecutive blocks
  int qi = 31 - (bid >> 5);          // heavy q-tiles dispatched first
  int q0 = qi << 6;
  int b = bh >> 4, h = bh & 15;
  int W = *winp;
  int tid = threadIdx.x;
  int wid = tid >> 6, l = tid & 63, lr = l & 15, lg = l >> 4;

  __shared__ u16 Kl[64][72];       // [key][d]
  __shared__ u16 Vt[64][72];       // [d][key]  (staged from KVt, b128 rows)
  __shared__ u16 Pl[4][16][72];    // per-wave P tile [q][key]

  const u16* Qb = Q + (((size_t)bh * T + q0 + wid * 16 + lr) << 6);
  short8v aq0 = *reinterpret_cast<const short8v*>(Qb + lg * 8);
  short8v aq1 = *reinterpret_cast<const short8v*>(Qb + 32 + lg * 8);

  const short one_bf = (short)0x3F80;
  short8v vones = {one_bf, one_bf, one_bf, one_bf, one_bf, one_bf, one_bf, one_bf};

  float m_run[4], l_run[4];
  f32x4 oacc[4];
#pragma unroll
  for (int r = 0; r < 4; r++) { m_run[r] = -1e30f; l_run[r] = 0.f; }
#pragma unroll
  for (int dt = 0; dt < 4; dt++) oacc[dt] = (f32x4){0.f, 0.f, 0.f, 0.f};

  int lo = q0 - W;
  if (lo < 0) lo = 0;
  lo &= ~63;

  const u16* KVbh  = KV + (((size_t)bh * T) << 6);
  const u16* KVtbh = KVt + ((size_t)bh << 6) * T;
  int r8 = tid >> 3, sg = tid & 7;   // staging: rows r8 and r8+32, col seg sg

  // T14: prefetch first tile into registers (issue early / LDS-write late)
  short8v vK0 = *reinterpret_cast<const short8v*>(KVbh + ((size_t)(lo + r8) << 6) + sg * 8);
  short8v vK1 = *reinterpret_cast<const short8v*>(KVbh + ((size_t)(lo + r8 + 32) << 6) + sg * 8);
  short8v vV0 = *reinterpret_cast<const short8v*>(KVtbh + (size_t)r8 * T + lo + sg * 8);
  short8v vV1 = *reinterpret_cast<const short8v*>(KVtbh + (size_t)(r8 + 32) * T + lo + sg * 8);

  for (int kt = lo; kt <= q0; kt += 64) {
    __syncthreads();                 // prev compute done reading LDS
    *reinterpret_cast<short8v*>(&Kl[r8][sg * 8]) = vK0;
    *reinterpret_cast<short8v*>(&Kl[r8 + 32][sg * 8]) = vK1;
    *reinterpret_cast<short8v*>(&Vt[r8][sg * 8]) = vV0;
    *reinterpret_cast<short8v*>(&Vt[r8 + 32][sg * 8]) = vV1;
    __syncthreads();                 // tile ready
    if (kt < q0) {                   // prefetch next tile under compute
      vK0 = *reinterpret_cast<const short8v*>(KVbh + ((size_t)(kt + 64 + r8) << 6) + sg * 8);
      vK1 = *reinterpret_cast<const short8v*>(KVbh + ((size_t)(kt + 64 + r8 + 32) << 6) + sg * 8);
      vV0 = *reinterpret_cast<const short8v*>(KVtbh + (size_t)r8 * T + kt + 64 + sg * 8);
      vV1 = *reinterpret_cast<const short8v*>(KVtbh + (size_t)(r8 + 32) * T + kt + 64 + sg * 8);
    }

    // S = Q K^T  (16q x 64keys per wave), already in exp2 domain (q pre-scaled)
    f32x4 s[4];
#pragma unroll
    for (int nt = 0; nt < 4; nt++) {
      s[nt] = (f32x4){0.f, 0.f, 0.f, 0.f};
      short8v b0 = *reinterpret_cast<const short8v*>(&Kl[nt * 16 + lr][lg * 8]);
      s[nt] = MFMA16(aq0, b0, s[nt]);
      short8v b1 = *reinterpret_cast<const short8v*>(&Kl[nt * 16 + lr][32 + lg * 8]);
      s[nt] = MFMA16(aq1, b1, s[nt]);
    }

    // masking needed only on the diagonal tile (causal) and the window-edge
    // tile; wave-uniform test.
    bool edge = (kt + 63 > q0 + wid * 16) || ((q0 - kt) + wid * 16 + 15 > W);

    float al4[4];
#pragma unroll
    for (int r = 0; r < 4; r++) {
      float sv[4], mt;
      if (edge) {
        int t = q0 + wid * 16 + lg * 4 + r;
        mt = -3e38f;
#pragma unroll
        for (int nt = 0; nt < 4; nt++) {
          int k = kt + nt * 16 + lr;
          float val = ((k <= t) && (t - k <= W)) ? s[nt][r] : -3e38f;
          sv[nt] = val;
          mt = fmaxf(mt, val);
        }
      } else {
#pragma unroll
        for (int nt = 0; nt < 4; nt++) sv[nt] = s[nt][r];
        mt = fmaxf(fmaxf(sv[0], sv[1]), fmaxf(sv[2], sv[3]));
      }
      mt = fmaxf(mt, __shfl_xor(mt, 1));
      mt = fmaxf(mt, __shfl_xor(mt, 2));
      mt = fmaxf(mt, __shfl_xor(mt, 4));
      mt = fmaxf(mt, __shfl_xor(mt, 8));
      float mn = fmaxf(m_run[r], mt);
      float al = exp2f(m_run[r] - mn);
      m_run[r] = mn;
      al4[r] = al;
#pragma unroll
      for (int nt = 0; nt < 4; nt++) {
        Pl[wid][lg * 4 + r][nt * 16 + lr] = f2bf(exp2f(sv[nt] - mn));
      }
#pragma unroll
      for (int dt = 0; dt < 4; dt++) oacc[dt][r] *= al;
    }

    // O += P V ; row-sum of P via ones-MFMA on the idle matrix pipe
    short8v ap0 = *reinterpret_cast<const short8v*>(&Pl[wid][lr][lg * 8]);
    short8v ap1 = *reinterpret_cast<const short8v*>(&Pl[wid][lr][32 + lg * 8]);
    f32x4 psum = (f32x4){0.f, 0.f, 0.f, 0.f};
    psum = MFMA16(ap0, vones, psum);
    psum = MFMA16(ap1, vones, psum);
#pragma unroll
    for (int dt = 0; dt < 4; dt++) {
      short8v v0 = *reinterpret_cast<const short8v*>(&Vt[dt * 16 + lr][lg * 8]);
      oacc[dt] = MFMA16(ap0, v0, oacc[dt]);
      short8v v1 = *reinterpret_cast<const short8v*>(&Vt[dt * 16 + lr][32 + lg * 8]);
      oacc[dt] = MFMA16(ap1, v1, oacc[dt]);
    }
#pragma unroll
    for (int r = 0; r < 4; r++) l_run[r] = l_run[r] * al4[r] + psum[r];
  }

  // epilogue: O (B,T,C) bf16
#pragma unroll
  for (int r = 0; r < 4; r++) {
    int t = q0 + wid * 16 + lg * 4 + r;
    float inv = 1.f / l_run[r];
#pragma unroll
    for (int dt = 0; dt < 4; dt++) {
      O[(((size_t)b * T + t) << 10) + (h << 6) + dt * 16 + lr] = f2bf(oacc[dt][r] * inv);
    }
  }
}

extern "C" void kernel_launch(void* const* d_in, const int* in_sizes, int n_in,
                              void* d_out, int out_size, void* d_ws, size_t ws_size,
                              hipStream_t stream) {
  (void)in_sizes; (void)n_in; (void)out_size; (void)ws_size;
  const float* x    = (const float*)d_in[0];
  const float* cosp = (const float*)d_in[1];
  const float* sinp = (const float*)d_in[2];
  const float* kvw  = (const float*)d_in[3];
  const float* pw   = (const float*)d_in[4];
  const int*   win  = (const int*)d_in[5];

  char* w = (char*)d_ws;
  u16*   xbf   = (u16*)(w);                        // 0-8MB: x bf16, then q (B,H,T,D)
  u16*   kvwbf = (u16*)(w + (8u << 20));           // 8-10MB
  u16*   pwbf  = (u16*)(w + (10u << 20));          // 10-12MB
  float* kvf   = (float*)(w + (12u << 20));        // 12-28MB kv fp32 (dead after rope2)
  u16*   kvt   = (u16*)(w + (12u << 20));          // 12-20MB (over dead kvf)
  u16*   aout  = (u16*)(w + (20u << 20));          // 20-28MB (over dead kvf)
  u16*   kvbf  = (u16*)(w + (28u << 20));          // 28-36MB
  u16*   qbf   = xbf;

  cast_f32_bf16<<<4096, 256, 0, stream>>>(x, xbf, 4194304);
  cast_f32_bf16<<<1024, 256, 0, stream>>>(kvw, kvwbf, 1048576);
  cast_f32_bf16<<<1024, 256, 0, stream>>>(pw, pwbf, 1048576);

  // kv = x @ kv_w^T   (4096 x 1024 x 1024)
  gemm_bt<<<dim3(64, 8), 256, 0, stream>>>(xbf, kvwbf, kvf, 4096, 1024, 1024);

  // q = rmsnorm(rotary(x)) * 0.125*log2e;  kv = rmsnorm(rotary(kv))
  rope_rms<<<16384, 256, 0, stream>>>(x, qbf, cosp, sinp, 0.18033688011112042f);
  rope_rms<<<16384, 256, 0, stream>>>(kvf, kvbf, cosp, sinp, 1.0f);

  // kvt (B,H,D,T) for the PV B-operand
  transpose_td<<<dim3(32, 32), 256, 0, stream>>>(kvbf, kvt);

  // sliding-window attention -> (B,T,C) bf16
  attn_swa<<<1024, 256, 0, stream>>>(qbf, kvbf, kvt, aout, win);

  // out = attn_out @ proj_w^T -> fp32
  gemm_bt<<<dim3(64, 8), 256, 0, stream>>>(aout, pwbf, (float*)d_out, 4096, 1024, 1024);
}

// Round 5
// 199.509 us; speedup vs baseline: 1.1973x; 1.0221x over previous
//
#include <hip/hip_runtime.h>
#include <hip/hip_bf16.h>

using u16 = unsigned short;
typedef __attribute__((ext_vector_type(8))) short short8v;
typedef __attribute__((ext_vector_type(4))) float f32x4;

#define MFMA16(a, b, c) __builtin_amdgcn_mfma_f32_16x16x32_bf16((a), (b), (c), 0, 0, 0)

#define GLOAD16(g, l) __builtin_amdgcn_global_load_lds(                       \
    (const __attribute__((address_space(1))) void*)(const void*)(g),          \
    (__attribute__((address_space(3))) void*)(void*)(l), 16, 0, 0)

static __device__ __forceinline__ u16 f2bf(float x) {
  __hip_bfloat16 h = __float2bfloat16(x);
  return __builtin_bit_cast(u16, h);
}

__global__ __launch_bounds__(256) void cast_f32_bf16(const float* __restrict__ s,
                                                     u16* __restrict__ d, int n) {
  int i = (blockIdx.x * 256 + threadIdx.x) * 4;
  if (i >= n) return;
  float4 v = *reinterpret_cast<const float4*>(s + i);
  ushort4 o;
  o.x = f2bf(v.x); o.y = f2bf(v.y); o.z = f2bf(v.z); o.w = f2bf(v.w);
  *reinterpret_cast<ushort4*>(d + i) = o;
}

// C[M,N] fp32 = A[M,K] bf16 @ Bt[N,K]^T.  BM=64 BN=128 BK=32, 4 waves (2x2).
// 2-phase pipeline: double-buffered LDS, global_load_lds for tile t+1 issued
// BEFORE ds_read+MFMA of tile t; one __syncthreads (vmcnt0 drain) per step.
// XCD swizzle: each XCD owns one bn panel -> B panel L2-resident (2MB < 4MB).
__global__ __launch_bounds__(256) void gemm_bt(const u16* __restrict__ A,
                                               const u16* __restrict__ Bt,
                                               float* __restrict__ C,
                                               int M, int N, int K) {
  __shared__ u16 As[2][64 * 32];
  __shared__ u16 Bs[2][128 * 32];
  unsigned flat = blockIdx.y * gridDim.x + blockIdx.x;
  unsigned nwg = gridDim.x * gridDim.y;
  unsigned swz = (flat & 7) * (nwg >> 3) + (flat >> 3);  // nwg % 8 == 0
  int bm = swz % gridDim.x, bn = swz / gridDim.x;
  int tid = threadIdx.x;
  int wid = tid >> 6, l = tid & 63, lr = l & 15, lg = l >> 4;
  int wr = wid >> 1, wc = wid & 1;

  // staging: per gload a wave covers 16 rows x 32 elems (lane l -> row l>>2,
  // 16B chunk l&3); LDS dest = wave-uniform base + lane*16B (linear).
  int srow = l >> 2, scol = (l & 3) * 8;
  const u16* Ag  = A  + (size_t)(bm * 64 + wid * 16 + srow) * K + scol;
  const u16* Bg0 = Bt + (size_t)(bn * 128 + wid * 32 + srow) * K + scol;
  const u16* Bg1 = Bg0 + (size_t)16 * K;

  f32x4 acc[2][4];
#pragma unroll
  for (int m = 0; m < 2; m++)
#pragma unroll
    for (int n = 0; n < 4; n++) acc[m][n] = (f32x4){0.f, 0.f, 0.f, 0.f};

  // prologue: stage k-tile 0 into buffer 0
  GLOAD16(Ag, &As[0][wid * 512]);
  GLOAD16(Bg0, &Bs[0][wid * 1024]);
  GLOAD16(Bg1, &Bs[0][wid * 1024 + 512]);
  __syncthreads();  // drains vmcnt(0): tile 0 resident

  int cur = 0;
  for (int k0 = 0; k0 < K; k0 += 32) {
    if (k0 + 32 < K) {  // issue next tile's loads; they fly under MFMA below
      int nb = cur ^ 1;
      GLOAD16(Ag + k0 + 32, &As[nb][wid * 512]);
      GLOAD16(Bg0 + k0 + 32, &Bs[nb][wid * 1024]);
      GLOAD16(Bg1 + k0 + 32, &Bs[nb][wid * 1024 + 512]);
    }

    short8v af[2], bfr[4];
#pragma unroll
    for (int m = 0; m < 2; m++)
      af[m] = *reinterpret_cast<const short8v*>(&As[cur][(wr * 32 + m * 16 + lr) * 32 + lg * 8]);
#pragma unroll
    for (int n = 0; n < 4; n++)
      bfr[n] = *reinterpret_cast<const short8v*>(&Bs[cur][(wc * 64 + n * 16 + lr) * 32 + lg * 8]);
#pragma unroll
    for (int m = 0; m < 2; m++)
#pragma unroll
      for (int n = 0; n < 4; n++) acc[m][n] = MFMA16(af[m], bfr[n], acc[m][n]);

    __syncthreads();  // drains vmcnt(0)+lgkmcnt: next tile ready, reads done
    cur ^= 1;
  }

#pragma unroll
  for (int m = 0; m < 2; m++)
#pragma unroll
    for (int n = 0; n < 4; n++)
#pragma unroll
      for (int r = 0; r < 4; r++) {
        int row = bm * 64 + wr * 32 + m * 16 + lg * 4 + r;
        int col = bn * 128 + wc * 64 + n * 16 + lr;
        C[(size_t)row * N + col] = acc[m][n][r];
      }
}

// fused rotary + rms_norm (+ output scale): one wave per (b,t,h) row of 64.
// src layout (B,T,H,D) fp32; dst layout (B,H,T,D) bf16.
__global__ __launch_bounds__(256) void rope_rms(const float* __restrict__ src,
                                                u16* __restrict__ dst,
                                                const float* __restrict__ cosp,
                                                const float* __restrict__ sinp,
                                                float scale) {
  int R = blockIdx.x * 4 + (threadIdx.x >> 6);  // R = (b*T + t)*H + h
  int l = threadIdx.x & 63;
  int h = R & 15;
  int bt = R >> 4;
  int t = bt & 2047, b = bt >> 11;

  float v = src[((size_t)R << 6) + l];
  float p = __shfl_xor(v, 32);
  float c = cosp[(t << 5) + (l & 31)];
  float s = sinp[(t << 5) + (l & 31)];
  float r = v * c + ((l < 32) ? p * s : -p * s);
  float sq = r * r;
  sq += __shfl_xor(sq, 32);
  sq += __shfl_xor(sq, 16);
  sq += __shfl_xor(sq, 8);
  sq += __shfl_xor(sq, 4);
  sq += __shfl_xor(sq, 2);
  sq += __shfl_xor(sq, 1);
  float inv = rsqrtf(sq * (1.0f / 64.0f) + 1.1920928955078125e-07f) * scale;
  dst[((((size_t)b * 16 + h) * 2048 + t) << 6) + l] = f2bf(r * inv);
}

// (BH,T,D) -> (BH,D,T) bf16 transpose in 64x64 tiles.
__global__ __launch_bounds__(256) void transpose_td(const u16* __restrict__ src,
                                                    u16* __restrict__ dst) {
  __shared__ u16 Ld[64][72];
  int t0 = blockIdx.x << 6, bh = blockIdx.y;
  int tid = threadIdx.x;
#pragma unroll
  for (int i = 0; i < 2; i++) {
    int c = tid + i * 256, tr = c >> 3, sg = c & 7;
    *reinterpret_cast<short8v*>(&Ld[tr][sg * 8]) =
        *reinterpret_cast<const short8v*>(src + ((size_t)bh * 2048 + t0 + tr) * 64 + sg * 8);
  }
  __syncthreads();
#pragma unroll
  for (int i = 0; i < 2; i++) {
    int c = tid + i * 256, dr = c >> 3, sg = c & 7;
    short8v v;
#pragma unroll
    for (int j = 0; j < 8; j++) v[j] = (short)Ld[sg * 8 + j][dr];
    *reinterpret_cast<short8v*>(dst + ((size_t)bh * 64 + dr) * 2048 + t0 + sg * 8) = v;
  }
}

// sliding-window flash attention. Q: (B,H,T,D) bf16 PRE-SCALED by 0.125*log2e;
// KV: (B,H,T,D); KVt: (B,H,D,T). O: (B,T,H*D) bf16. Softmax in exp2 domain.
// 1 block = (b,h, 64 q rows); 4 waves x 16 q rows. K=V (single kv tensor).
__global__ __launch_bounds__(256) void attn_swa(const u16* __restrict__ Q,
                                                const u16* __restrict__ KV,
                                                const u16* __restrict__ KVt,
                                                u16* __restrict__ O,
                                                const int* __restrict__ winp) {
  const int T = 2048;
  int bid = blockIdx.x;
  int bh = bid & 31;                 // spread bh across consecutive blocks
  int qi = 31 - (bid >> 5);          // heavy q-tiles dispatched first
  int q0 = qi << 6;
  int b = bh >> 4, h = bh & 15;
  int W = *winp;
  int tid = threadIdx.x;
  int wid = tid >> 6, l = tid & 63, lr = l & 15, lg = l >> 4;

  __shared__ u16 Kl[64][72];       // [key][d]
  __shared__ u16 Vt[64][72];       // [d][key]  (staged from KVt, b128 rows)
  __shared__ u16 Pl[4][16][72];    // per-wave P tile [q][key]

  const u16* Qb = Q + (((size_t)bh * T + q0 + wid * 16 + lr) << 6);
  short8v aq0 = *reinterpret_cast<const short8v*>(Qb + lg * 8);
  short8v aq1 = *reinterpret_cast<const short8v*>(Qb + 32 + lg * 8);

  const short one_bf = (short)0x3F80;
  short8v vones = {one_bf, one_bf, one_bf, one_bf, one_bf, one_bf, one_bf, one_bf};

  float m_run[4], l_run[4];
  f32x4 oacc[4];
#pragma unroll
  for (int r = 0; r < 4; r++) { m_run[r] = -1e30f; l_run[r] = 0.f; }
#pragma unroll
  for (int dt = 0; dt < 4; dt++) oacc[dt] = (f32x4){0.f, 0.f, 0.f, 0.f};

  int lo = q0 - W;
  if (lo < 0) lo = 0;
  lo &= ~63;

  const u16* KVbh  = KV + (((size_t)bh * T) << 6);
  const u16* KVtbh = KVt + ((size_t)bh << 6) * T;
  int r8 = tid >> 3, sg = tid & 7;   // staging: rows r8 and r8+32, col seg sg

  // T14: prefetch first tile into registers (issue early / LDS-write late)
  short8v vK0 = *reinterpret_cast<const short8v*>(KVbh + ((size_t)(lo + r8) << 6) + sg * 8);
  short8v vK1 = *reinterpret_cast<const short8v*>(KVbh + ((size_t)(lo + r8 + 32) << 6) + sg * 8);
  short8v vV0 = *reinterpret_cast<const short8v*>(KVtbh + (size_t)r8 * T + lo + sg * 8);
  short8v vV1 = *reinterpret_cast<const short8v*>(KVtbh + (size_t)(r8 + 32) * T + lo + sg * 8);

  for (int kt = lo; kt <= q0; kt += 64) {
    __syncthreads();                 // prev compute done reading LDS
    *reinterpret_cast<short8v*>(&Kl[r8][sg * 8]) = vK0;
    *reinterpret_cast<short8v*>(&Kl[r8 + 32][sg * 8]) = vK1;
    *reinterpret_cast<short8v*>(&Vt[r8][sg * 8]) = vV0;
    *reinterpret_cast<short8v*>(&Vt[r8 + 32][sg * 8]) = vV1;
    __syncthreads();                 // tile ready
    if (kt < q0) {                   // prefetch next tile under compute
      vK0 = *reinterpret_cast<const short8v*>(KVbh + ((size_t)(kt + 64 + r8) << 6) + sg * 8);
      vK1 = *reinterpret_cast<const short8v*>(KVbh + ((size_t)(kt + 64 + r8 + 32) << 6) + sg * 8);
      vV0 = *reinterpret_cast<const short8v*>(KVtbh + (size_t)r8 * T + kt + 64 + sg * 8);
      vV1 = *reinterpret_cast<const short8v*>(KVtbh + (size_t)(r8 + 32) * T + kt + 64 + sg * 8);
    }

    // S = Q K^T  (16q x 64keys per wave), already in exp2 domain (q pre-scaled)
    f32x4 s[4];
#pragma unroll
    for (int nt = 0; nt < 4; nt++) {
      s[nt] = (f32x4){0.f, 0.f, 0.f, 0.f};
      short8v b0 = *reinterpret_cast<const short8v*>(&Kl[nt * 16 + lr][lg * 8]);
      s[nt] = MFMA16(aq0, b0, s[nt]);
      short8v b1 = *reinterpret_cast<const short8v*>(&Kl[nt * 16 + lr][32 + lg * 8]);
      s[nt] = MFMA16(aq1, b1, s[nt]);
    }

    // masking needed only on the diagonal tile (causal) and the window-edge
    // tile; wave-uniform test.
    bool edge = (kt + 63 > q0 + wid * 16) || ((q0 - kt) + wid * 16 + 15 > W);

    float al4[4];
#pragma unroll
    for (int r = 0; r < 4; r++) {
      float sv[4], mt;
      if (edge) {
        int t = q0 + wid * 16 + lg * 4 + r;
        mt = -3e38f;
#pragma unroll
        for (int nt = 0; nt < 4; nt++) {
          int k = kt + nt * 16 + lr;
          float val = ((k <= t) && (t - k <= W)) ? s[nt][r] : -3e38f;
          sv[nt] = val;
          mt = fmaxf(mt, val);
        }
      } else {
#pragma unroll
        for (int nt = 0; nt < 4; nt++) sv[nt] = s[nt][r];
        mt = fmaxf(fmaxf(sv[0], sv[1]), fmaxf(sv[2], sv[3]));
      }
      mt = fmaxf(mt, __shfl_xor(mt, 1));
      mt = fmaxf(mt, __shfl_xor(mt, 2));
      mt = fmaxf(mt, __shfl_xor(mt, 4));
      mt = fmaxf(mt, __shfl_xor(mt, 8));
      float mn = fmaxf(m_run[r], mt);
      float al = exp2f(m_run[r] - mn);
      m_run[r] = mn;
      al4[r] = al;
#pragma unroll
      for (int nt = 0; nt < 4; nt++) {
        Pl[wid][lg * 4 + r][nt * 16 + lr] = f2bf(exp2f(sv[nt] - mn));
      }
#pragma unroll
      for (int dt = 0; dt < 4; dt++) oacc[dt][r] *= al;
    }

    // O += P V ; row-sum of P via ones-MFMA on the idle matrix pipe
    short8v ap0 = *reinterpret_cast<const short8v*>(&Pl[wid][lr][lg * 8]);
    short8v ap1 = *reinterpret_cast<const short8v*>(&Pl[wid][lr][32 + lg * 8]);
    f32x4 psum = (f32x4){0.f, 0.f, 0.f, 0.f};
    psum = MFMA16(ap0, vones, psum);
    psum = MFMA16(ap1, vones, psum);
#pragma unroll
    for (int dt = 0; dt < 4; dt++) {
      short8v v0 = *reinterpret_cast<const short8v*>(&Vt[dt * 16 + lr][lg * 8]);
      oacc[dt] = MFMA16(ap0, v0, oacc[dt]);
      short8v v1 = *reinterpret_cast<const short8v*>(&Vt[dt * 16 + lr][32 + lg * 8]);
      oacc[dt] = MFMA16(ap1, v1, oacc[dt]);
    }
#pragma unroll
    for (int r = 0; r < 4; r++) l_run[r] = l_run[r] * al4[r] + psum[r];
  }

  // epilogue: O (B,T,C) bf16
#pragma unroll
  for (int r = 0; r < 4; r++) {
    int t = q0 + wid * 16 + lg * 4 + r;
    float inv = 1.f / l_run[r];
#pragma unroll
    for (int dt = 0; dt < 4; dt++) {
      O[(((size_t)b * T + t) << 10) + (h << 6) + dt * 16 + lr] = f2bf(oacc[dt][r] * inv);
    }
  }
}

extern "C" void kernel_launch(void* const* d_in, const int* in_sizes, int n_in,
                              void* d_out, int out_size, void* d_ws, size_t ws_size,
                              hipStream_t stream) {
  (void)in_sizes; (void)n_in; (void)out_size; (void)ws_size;
  const float* x    = (const float*)d_in[0];
  const float* cosp = (const float*)d_in[1];
  const float* sinp = (const float*)d_in[2];
  const float* kvw  = (const float*)d_in[3];
  const float* pw   = (const float*)d_in[4];
  const int*   win  = (const int*)d_in[5];

  char* w = (char*)d_ws;
  u16*   xbf   = (u16*)(w);                        // 0-8MB: x bf16, then q (B,H,T,D)
  u16*   kvwbf = (u16*)(w + (8u << 20));           // 8-10MB
  u16*   pwbf  = (u16*)(w + (10u << 20));          // 10-12MB
  float* kvf   = (float*)(w + (12u << 20));        // 12-28MB kv fp32 (dead after rope2)
  u16*   kvt   = (u16*)(w + (12u << 20));          // 12-20MB (over dead kvf)
  u16*   aout  = (u16*)(w + (20u << 20));          // 20-28MB (over dead kvf)
  u16*   kvbf  = (u16*)(w + (28u << 20));          // 28-36MB
  u16*   qbf   = xbf;

  cast_f32_bf16<<<4096, 256, 0, stream>>>(x, xbf, 4194304);
  cast_f32_bf16<<<1024, 256, 0, stream>>>(kvw, kvwbf, 1048576);
  cast_f32_bf16<<<1024, 256, 0, stream>>>(pw, pwbf, 1048576);

  // kv = x @ kv_w^T   (4096 x 1024 x 1024)
  gemm_bt<<<dim3(64, 8), 256, 0, stream>>>(xbf, kvwbf, kvf, 4096, 1024, 1024);

  // q = rmsnorm(rotary(x)) * 0.125*log2e;  kv = rmsnorm(rotary(kv))
  rope_rms<<<16384, 256, 0, stream>>>(x, qbf, cosp, sinp, 0.18033688011112042f);
  rope_rms<<<16384, 256, 0, stream>>>(kvf, kvbf, cosp, sinp, 1.0f);

  // kvt (B,H,D,T) for the PV B-operand
  transpose_td<<<dim3(32, 32), 256, 0, stream>>>(kvbf, kvt);

  // sliding-window attention -> (B,T,C) bf16
  attn_swa<<<1024, 256, 0, stream>>>(qbf, kvbf, kvt, aout, win);

  // out = attn_out @ proj_w^T -> fp32
  gemm_bt<<<dim3(64, 8), 256, 0, stream>>>(aout, pwbf, (float*)d_out, 4096, 1024, 1024);
}